// Round 9
// baseline (216.258 us; speedup 1.0000x reference)
//
#include <hip/hip_runtime.h>

#define C_DIM 256
#define K_DIM 128
#define HW_DIM 64
#define PIX 4096
#define N_IMG 32

using short8 = __attribute__((ext_vector_type(8))) short;
using f32x4  = __attribute__((ext_vector_type(4))) float;

// CK-style barrier: waits own LDS ops (lgkmcnt) only — leaves global-load
// prefetches (vmcnt) in flight across the barrier, unlike __syncthreads().
__device__ __forceinline__ void lds_barrier() {
    asm volatile("s_waitcnt lgkmcnt(0)\n\ts_barrier" ::: "memory");
}

__device__ __forceinline__ unsigned long long umin64(unsigned long long a, unsigned long long b) {
    return a < b ? a : b;
}
__device__ __forceinline__ unsigned mono(float d) {
    unsigned u = __float_as_uint(d);
    return u ^ ((u & 0x80000000u) ? 0xFFFFFFFFu : 0x80000000u);
}

// Truncation split: v = hi + mid + lo, each term = top-16-bit bitmask value
// (exact Sterbenz residuals; lo ~ 2^-16 * v). Cheap: and/sub only.
__device__ __forceinline__ void split3t(float v, unsigned& hu, unsigned& mu, unsigned& lu) {
    unsigned u = __float_as_uint(v);
    unsigned hf = u & 0xffff0000u;
    float r1 = v - __uint_as_float(hf);
    unsigned r1u = __float_as_uint(r1);
    unsigned mf = r1u & 0xffff0000u;
    float r2 = r1 - __uint_as_float(mf);
    hu = u; mu = r1u; lu = __float_as_uint(r2);   // consumers take >>16
}

// P: per cluster k: trunc 3-way split -> Bt[k][768] (planes hi/mid/lo) + exact c2
__global__ __launch_bounds__(64) void prep_kernel(const float* __restrict__ cl,
                                                  unsigned short* __restrict__ Bt,
                                                  float* __restrict__ c2) {
    int k = blockIdx.x;
    int lane = threadIdx.x;
    const float4* row = (const float4*)(cl + k * C_DIM);
    float4 v = row[lane];
    float vv[4] = {v.x, v.y, v.z, v.w};
    unsigned short* bk = Bt + k * 768 + lane * 4;
#pragma unroll
    for (int i = 0; i < 4; ++i) {
        unsigned hu, mu, lu;
        split3t(vv[i], hu, mu, lu);
        bk[i]       = (unsigned short)(hu >> 16);
        bk[256 + i] = (unsigned short)(mu >> 16);
        bk[512 + i] = (unsigned short)(lu >> 16);
    }
    if (lane == 0) {   // identical op order to proven-exact c2
        float s = 0.f;
#pragma unroll
        for (int i = 0; i < C_DIM / 4; ++i) {
            float4 u = row[i];
            s = fmaf(u.x, u.x, s);
            s = fmaf(u.y, u.y, s);
            s = fmaf(u.z, u.z, s);
            s = fmaf(u.w, u.w, s);
        }
        c2[k] = s;
    }
}

// Main: proven round-5 best with ONE change: bv loads hoisted to iteration
// top (BEFORE convert) so the ~300+ cyc convert VALU phase covers bv's L2
// latency — previously the first MFMA of every chunk ate that latency raw
// (only xr-issue + barrier-skew between bv issue and vmcnt wait). vmcnt
// FIFO preserved: bv(6) first, xr(16) behind, MFMA waits vmcnt(16) -> bv
// arrived, xr in flight across both barriers. Fits the 128-reg cap thanks
// to v_perm packing (peak ~ acc64 + bv24 + xr16 + temps ~ 120).
// Everything else identical to measured-best R5: block = 256 thr (4 waves),
// S[128px][128k] via 16x16x32 bf16 MFMA, 6 cross-term pairs, per-acc term
// order (0,0)(0,1)(0,2)(1,0)(1,1)(2,0) over ascending chunks, 4 blocks/CU,
// setprio around MFMA, fused exact-dyadic histogram epilogue.
__global__ __launch_bounds__(256, 4) void main_kernel(
    const float* __restrict__ x, const unsigned short* __restrict__ Bt,
    const float* __restrict__ c2v, float* __restrict__ out) {

    __shared__ __align__(16) unsigned short Ap[3 * 4096];   // 24576 B
    __shared__ float x2p[2][128];                           // 1024 B
    unsigned long long* red = (unsigned long long*)Ap;      // aliased (epilogue only)

    const int t    = threadIdx.x;
    const int lane = t & 63;
    const int w    = t >> 6;
    const int q    = lane >> 4;
    const int l15  = lane & 15;

    const int px = t & 127;        // conversion: this thread's pixel row
    const int h  = t >> 7;         // conversion: c-half (0: c 0-15, 1: c 16-31)

    const int b   = blockIdx.x;
    const int img = b >> 5;
    const int pb  = (b & 31) * 128;

    const float* xg = x + (size_t)img * (C_DIM * PIX) + pb + px;

    f32x4 acc[8][2];
#pragma unroll
    for (int m = 0; m < 8; ++m)
#pragma unroll
        for (int ns = 0; ns < 2; ++ns) acc[m][ns] = (f32x4){0.f, 0.f, 0.f, 0.f};

    float xr[16];
#pragma unroll
    for (int j = 0; j < 16; ++j) xr[j] = xg[(size_t)(h * 16 + j) * PIX];

    float x2part = 0.f;
    const unsigned short* btb = Bt + (w * 32 + l15) * 768 + q * 8;

    // convert-phase LDS write base (ushort idx within a plane)
    const int wbase = (px >> 4) * 512 + (px & 15) * 8 + h * 2 * 128;

#pragma unroll 1
    for (int ci = 0; ci < 8; ++ci) {
        // ---- B-fragments FIRST: 6 unique (plane x n-half), L2-hot,
        // imm-folded addressing. Convert below covers their latency.
        short8 bv[3][2];
#pragma unroll
        for (int p = 0; p < 3; ++p) {
            bv[p][0] = *(const short8*)(btb + p * 256 + ci * 32);
            bv[p][1] = *(const short8*)(btb + 16 * 768 + p * 256 + ci * 32);
        }

        // ---- convert xr -> 3 bf16 planes in LDS (trunc split + perm) + x2 ----
#pragma unroll
        for (int g = 0; g < 2; ++g) {
            unsigned p0[4], p1[4], p2[4];
#pragma unroll
            for (int jj = 0; jj < 4; ++jj) {
                float v0 = xr[g * 8 + jj * 2], v1 = xr[g * 8 + jj * 2 + 1];
                unsigned h0, m0, l0, h1, m1, l1;
                split3t(v0, h0, m0, l0);
                split3t(v1, h1, m1, l1);
                // bytes [h0.b2,h0.b3,h1.b2,h1.b3] == (h0>>16)|(h1&0xffff0000)
                p0[jj] = __builtin_amdgcn_perm(h1, h0, 0x07060302u);
                p1[jj] = __builtin_amdgcn_perm(m1, m0, 0x07060302u);
                p2[jj] = __builtin_amdgcn_perm(l1, l0, 0x07060302u);
                x2part = fmaf(v0, v0, x2part);
                x2part = fmaf(v1, v1, x2part);
            }
            int base = wbase + g * 128;   // (q = h*2+g) * 16 lanes * 8 ushorts
            *(uint4*)&Ap[base]            = make_uint4(p0[0], p0[1], p0[2], p0[3]);
            *(uint4*)&Ap[4096 + base]     = make_uint4(p1[0], p1[1], p1[2], p1[3]);
            *(uint4*)&Ap[8192 + base]     = make_uint4(p2[0], p2[1], p2[2], p2[3]);
        }
        if (ci == 7) x2p[h][px] = x2part;

        // ---- prefetch next x chunk (vmcnt survives the barriers below;
        // issued behind bv so MFMA's vmcnt(16) wait covers bv only) ----
        if (ci < 7) {
#pragma unroll
            for (int j = 0; j < 16; ++j)
                xr[j] = xg[(size_t)((ci + 1) * 32 + h * 16 + j) * PIX];
        }

        lds_barrier();   // Ap ready (LDS-only wait)

        // ---- MFMA: pa outer, m-pairs, pb inner; per-acc term order =
        // pa ascending then pb ascending (identical to proven rounds).
        __builtin_amdgcn_s_setprio(1);
#pragma unroll
        for (int pa = 0; pa < 3; ++pa) {
#pragma unroll
            for (int mg = 0; mg < 4; ++mg) {
                const int m0 = mg * 2, m1 = mg * 2 + 1;
                short8 af0 = *(const short8*)&Ap[pa * 4096 + m0 * 512 + lane * 8];
                short8 af1 = *(const short8*)&Ap[pa * 4096 + m1 * 512 + lane * 8];
#pragma unroll
                for (int pb2 = 0; pb2 < 3; ++pb2) {
                    if (pb2 < 3 - pa) {
                        acc[m0][0] = __builtin_amdgcn_mfma_f32_16x16x32_bf16(af0, bv[pb2][0], acc[m0][0], 0, 0, 0);
                        acc[m0][1] = __builtin_amdgcn_mfma_f32_16x16x32_bf16(af0, bv[pb2][1], acc[m0][1], 0, 0, 0);
                        acc[m1][0] = __builtin_amdgcn_mfma_f32_16x16x32_bf16(af1, bv[pb2][0], acc[m1][0], 0, 0, 0);
                        acc[m1][1] = __builtin_amdgcn_mfma_f32_16x16x32_bf16(af1, bv[pb2][1], acc[m1][1], 0, 0, 0);
                    }
                }
            }
        }
        __builtin_amdgcn_s_setprio(0);
        lds_barrier();   // all Ap reads done before next convert overwrites
    }

    // ---- epilogue: dist = (x2 - 2*S) + c2, argmin (proven exact) ----
    const float c2a0 = c2v[w * 32 + l15];
    const float c2a1 = c2v[w * 32 + 16 + l15];
    const unsigned n0 = (unsigned)(w * 32 + l15);
    const unsigned n1 = n0 + 16;

#pragma unroll
    for (int m = 0; m < 8; ++m) {
#pragma unroll
        for (int r = 0; r < 4; ++r) {
            int pxl = m * 16 + q * 4 + r;             // C/D: row = quad*4 + reg
            float x2v = x2p[0][pxl] + x2p[1][pxl];
            float d0 = (x2v - 2.0f * acc[m][0][r]) + c2a0;
            float d1 = (x2v - 2.0f * acc[m][1][r]) + c2a1;
            unsigned long long k0 = ((unsigned long long)mono(d0) << 32) | n0;
            unsigned long long k1 = ((unsigned long long)mono(d1) << 32) | n1;
            unsigned long long best = umin64(k0, k1);
            best = umin64(best, __shfl_xor(best, 1));
            best = umin64(best, __shfl_xor(best, 2));
            best = umin64(best, __shfl_xor(best, 4));
            best = umin64(best, __shfl_xor(best, 8));
            if (l15 == 0) red[w * 128 + pxl] = best;
        }
    }
    lds_barrier();

    // ---- fused histogram: each t<128 owns pixel px=pb+t, adds 1/64 to its
    // (tile, code+1) cell. out zeroed by memsetAsync; k/64 sums are exact
    // fp32 dyadics -> order-independent, bitwise == count/64.
    if (t < 128) {
        unsigned long long m0 = umin64(umin64(red[t], red[128 + t]),
                                       umin64(red[256 + t], red[384 + t]));
        int c = (int)(m0 & 0xFFu);
        int p = pb + t;                    // pixel index in image
        int sy = (p >> 6) >> 3;            // row / 8
        int sx = (p & 63) >> 3;            // col / 8
        atomicAdd(&out[(size_t)img * (64 * (K_DIM + 1)) +
                       (sy * 8 + sx) * (K_DIM + 1) + c + 1],
                  0.015625f);              // 1/64
    }
}

extern "C" void kernel_launch(void* const* d_in, const int* in_sizes, int n_in,
                              void* d_out, int out_size, void* d_ws, size_t ws_size,
                              hipStream_t stream) {
    const float* x  = (const float*)d_in[0];       // (32, 256, 64, 64) fp32
    const float* cl = (const float*)d_in[1];       // (128, 256) fp32
    float* out = (float*)d_out;                    // (32, 64, 129) fp32

    unsigned short* Bt = (unsigned short*)d_ws;                  // 196608 B
    float* c2 = (float*)((char*)d_ws + 196608);                  // 512 B

    hipMemsetAsync(d_out, 0, (size_t)out_size, stream);
    prep_kernel<<<K_DIM, 64, 0, stream>>>(cl, Bt, c2);
    main_kernel<<<(N_IMG * PIX) / 128, 256, 0, stream>>>(x, Bt, c2, out);
}

// Round 10
// 213.527 us; speedup vs baseline: 1.0128x; 1.0128x over previous
//
#include <hip/hip_runtime.h>

#define C_DIM 256
#define K_DIM 128
#define HW_DIM 64
#define PIX 4096
#define N_IMG 32

using short8 = __attribute__((ext_vector_type(8))) short;
using f32x4  = __attribute__((ext_vector_type(4))) float;

// CK-style barrier: waits own LDS ops (lgkmcnt) only — leaves global-load
// prefetches (vmcnt) in flight across the barrier, unlike __syncthreads().
__device__ __forceinline__ void lds_barrier() {
    asm volatile("s_waitcnt lgkmcnt(0)\n\ts_barrier" ::: "memory");
}

__device__ __forceinline__ unsigned long long umin64(unsigned long long a, unsigned long long b) {
    return a < b ? a : b;
}
__device__ __forceinline__ unsigned mono(float d) {
    unsigned u = __float_as_uint(d);
    return u ^ ((u & 0x80000000u) ? 0xFFFFFFFFu : 0x80000000u);
}

// Truncation split: v = hi + mid + lo, each term = top-16-bit bitmask value
// (exact Sterbenz residuals; lo ~ 2^-16 * v). Cheap: and/sub only.
__device__ __forceinline__ void split3t(float v, unsigned& hu, unsigned& mu, unsigned& lu) {
    unsigned u = __float_as_uint(v);
    unsigned hf = u & 0xffff0000u;
    float r1 = v - __uint_as_float(hf);
    unsigned r1u = __float_as_uint(r1);
    unsigned mf = r1u & 0xffff0000u;
    float r2 = r1 - __uint_as_float(mf);
    hu = u; mu = r1u; lu = __float_as_uint(r2);   // consumers take >>16
}

// P: per cluster k: trunc 3-way split -> Bt[k][768] (planes hi/mid/lo) + exact c2
__global__ __launch_bounds__(64) void prep_kernel(const float* __restrict__ cl,
                                                  unsigned short* __restrict__ Bt,
                                                  float* __restrict__ c2) {
    int k = blockIdx.x;
    int lane = threadIdx.x;
    const float4* row = (const float4*)(cl + k * C_DIM);
    float4 v = row[lane];
    float vv[4] = {v.x, v.y, v.z, v.w};
    unsigned short* bk = Bt + k * 768 + lane * 4;
#pragma unroll
    for (int i = 0; i < 4; ++i) {
        unsigned hu, mu, lu;
        split3t(vv[i], hu, mu, lu);
        bk[i]       = (unsigned short)(hu >> 16);
        bk[256 + i] = (unsigned short)(mu >> 16);
        bk[512 + i] = (unsigned short)(lu >> 16);
    }
    if (lane == 0) {   // identical op order to proven-exact c2
        float s = 0.f;
#pragma unroll
        for (int i = 0; i < C_DIM / 4; ++i) {
            float4 u = row[i];
            s = fmaf(u.x, u.x, s);
            s = fmaf(u.y, u.y, s);
            s = fmaf(u.z, u.z, s);
            s = fmaf(u.w, u.w, s);
        }
        c2[k] = s;
    }
}

// Main: measured-best configuration (R5/R8, 214.3-214.7 us total), FINAL.
// Block = 256 thr (4 waves), S[128px][128k] via 16x16x32 bf16 MFMA, 6
// cross-term pairs; per-acc term order (0,0)(0,1)(0,2)(1,0)(1,1)(2,0) over
// ascending chunks. 4 blocks/CU via __launch_bounds__(256,4) — grid 1024 =
// 256 CU x 4, single uniform residency round. bv loads AFTER convert (short
// live range under the 128-reg cap; hoisting them regressed +2us in R9) and
// BEFORE the xr prefetch (vmcnt FIFO: first MFMA waits vmcnt(16), xr
// prefetch stays in flight across both barriers). v_perm packing;
// s_setprio(1) around MFMA phase; histogram fused into the epilogue (exact
// dyadic 1/64 atomic sums). Structural rewrites went 0-for-5 (dbuf-128,
// k-split-private, reg-direct-A, dbuf-64, bv-hoist) — this simple 2-barrier
// loop is the converged optimum: ~736 TF effective (~84% of the m97-class
// plain-HIP GEMM reference) with convert/x2/argmin/hist fused in.
__global__ __launch_bounds__(256, 4) void main_kernel(
    const float* __restrict__ x, const unsigned short* __restrict__ Bt,
    const float* __restrict__ c2v, float* __restrict__ out) {

    __shared__ __align__(16) unsigned short Ap[3 * 4096];   // 24576 B
    __shared__ float x2p[2][128];                           // 1024 B
    unsigned long long* red = (unsigned long long*)Ap;      // aliased (epilogue only)

    const int t    = threadIdx.x;
    const int lane = t & 63;
    const int w    = t >> 6;
    const int q    = lane >> 4;
    const int l15  = lane & 15;

    const int px = t & 127;        // conversion: this thread's pixel row
    const int h  = t >> 7;         // conversion: c-half (0: c 0-15, 1: c 16-31)

    const int b   = blockIdx.x;
    const int img = b >> 5;
    const int pb  = (b & 31) * 128;

    const float* xg = x + (size_t)img * (C_DIM * PIX) + pb + px;

    f32x4 acc[8][2];
#pragma unroll
    for (int m = 0; m < 8; ++m)
#pragma unroll
        for (int ns = 0; ns < 2; ++ns) acc[m][ns] = (f32x4){0.f, 0.f, 0.f, 0.f};

    float xr[16];
#pragma unroll
    for (int j = 0; j < 16; ++j) xr[j] = xg[(size_t)(h * 16 + j) * PIX];

    float x2part = 0.f;
    const unsigned short* btb = Bt + (w * 32 + l15) * 768 + q * 8;

    // convert-phase LDS write base (ushort idx within a plane)
    const int wbase = (px >> 4) * 512 + (px & 15) * 8 + h * 2 * 128;

#pragma unroll 1
    for (int ci = 0; ci < 8; ++ci) {
        // ---- convert xr -> 3 bf16 planes in LDS (trunc split + perm) + x2 ----
#pragma unroll
        for (int g = 0; g < 2; ++g) {
            unsigned p0[4], p1[4], p2[4];
#pragma unroll
            for (int jj = 0; jj < 4; ++jj) {
                float v0 = xr[g * 8 + jj * 2], v1 = xr[g * 8 + jj * 2 + 1];
                unsigned h0, m0, l0, h1, m1, l1;
                split3t(v0, h0, m0, l0);
                split3t(v1, h1, m1, l1);
                // bytes [h0.b2,h0.b3,h1.b2,h1.b3] == (h0>>16)|(h1&0xffff0000)
                p0[jj] = __builtin_amdgcn_perm(h1, h0, 0x07060302u);
                p1[jj] = __builtin_amdgcn_perm(m1, m0, 0x07060302u);
                p2[jj] = __builtin_amdgcn_perm(l1, l0, 0x07060302u);
                x2part = fmaf(v0, v0, x2part);
                x2part = fmaf(v1, v1, x2part);
            }
            int base = wbase + g * 128;   // (q = h*2+g) * 16 lanes * 8 ushorts
            *(uint4*)&Ap[base]            = make_uint4(p0[0], p0[1], p0[2], p0[3]);
            *(uint4*)&Ap[4096 + base]     = make_uint4(p1[0], p1[1], p1[2], p1[3]);
            *(uint4*)&Ap[8192 + base]     = make_uint4(p2[0], p2[1], p2[2], p2[3]);
        }
        if (ci == 7) x2p[h][px] = x2part;

        // ---- B-fragments: 6 unique (plane x n-half), L2-hot, imm-folded
        // addressing. Issued AFTER convert (short live range) but BEFORE the
        // xr prefetch (vmcnt FIFO keeps xr in flight past the MFMA's bv wait).
        short8 bv[3][2];
#pragma unroll
        for (int p = 0; p < 3; ++p) {
            bv[p][0] = *(const short8*)(btb + p * 256 + ci * 32);
            bv[p][1] = *(const short8*)(btb + 16 * 768 + p * 256 + ci * 32);
        }

        // ---- prefetch next x chunk (vmcnt survives the barriers below) ----
        if (ci < 7) {
#pragma unroll
            for (int j = 0; j < 16; ++j)
                xr[j] = xg[(size_t)((ci + 1) * 32 + h * 16 + j) * PIX];
        }

        lds_barrier();   // Ap ready (LDS-only wait)

        // ---- MFMA: pa outer, m-pairs, pb inner; per-acc term order =
        // pa ascending then pb ascending (identical to proven rounds).
        __builtin_amdgcn_s_setprio(1);
#pragma unroll
        for (int pa = 0; pa < 3; ++pa) {
#pragma unroll
            for (int mg = 0; mg < 4; ++mg) {
                const int m0 = mg * 2, m1 = mg * 2 + 1;
                short8 af0 = *(const short8*)&Ap[pa * 4096 + m0 * 512 + lane * 8];
                short8 af1 = *(const short8*)&Ap[pa * 4096 + m1 * 512 + lane * 8];
#pragma unroll
                for (int pb2 = 0; pb2 < 3; ++pb2) {
                    if (pb2 < 3 - pa) {
                        acc[m0][0] = __builtin_amdgcn_mfma_f32_16x16x32_bf16(af0, bv[pb2][0], acc[m0][0], 0, 0, 0);
                        acc[m0][1] = __builtin_amdgcn_mfma_f32_16x16x32_bf16(af0, bv[pb2][1], acc[m0][1], 0, 0, 0);
                        acc[m1][0] = __builtin_amdgcn_mfma_f32_16x16x32_bf16(af1, bv[pb2][0], acc[m1][0], 0, 0, 0);
                        acc[m1][1] = __builtin_amdgcn_mfma_f32_16x16x32_bf16(af1, bv[pb2][1], acc[m1][1], 0, 0, 0);
                    }
                }
            }
        }
        __builtin_amdgcn_s_setprio(0);
        lds_barrier();   // all Ap reads done before next convert overwrites
    }

    // ---- epilogue: dist = (x2 - 2*S) + c2, argmin (proven exact) ----
    const float c2a0 = c2v[w * 32 + l15];
    const float c2a1 = c2v[w * 32 + 16 + l15];
    const unsigned n0 = (unsigned)(w * 32 + l15);
    const unsigned n1 = n0 + 16;

#pragma unroll
    for (int m = 0; m < 8; ++m) {
#pragma unroll
        for (int r = 0; r < 4; ++r) {
            int pxl = m * 16 + q * 4 + r;             // C/D: row = quad*4 + reg
            float x2v = x2p[0][pxl] + x2p[1][pxl];
            float d0 = (x2v - 2.0f * acc[m][0][r]) + c2a0;
            float d1 = (x2v - 2.0f * acc[m][1][r]) + c2a1;
            unsigned long long k0 = ((unsigned long long)mono(d0) << 32) | n0;
            unsigned long long k1 = ((unsigned long long)mono(d1) << 32) | n1;
            unsigned long long best = umin64(k0, k1);
            best = umin64(best, __shfl_xor(best, 1));
            best = umin64(best, __shfl_xor(best, 2));
            best = umin64(best, __shfl_xor(best, 4));
            best = umin64(best, __shfl_xor(best, 8));
            if (l15 == 0) red[w * 128 + pxl] = best;
        }
    }
    lds_barrier();

    // ---- fused histogram: each t<128 owns pixel px=pb+t, adds 1/64 to its
    // (tile, code+1) cell. out zeroed by memsetAsync; k/64 sums are exact
    // fp32 dyadics -> order-independent, bitwise == count/64.
    if (t < 128) {
        unsigned long long m0 = umin64(umin64(red[t], red[128 + t]),
                                       umin64(red[256 + t], red[384 + t]));
        int c = (int)(m0 & 0xFFu);
        int p = pb + t;                    // pixel index in image
        int sy = (p >> 6) >> 3;            // row / 8
        int sx = (p & 63) >> 3;            // col / 8
        atomicAdd(&out[(size_t)img * (64 * (K_DIM + 1)) +
                       (sy * 8 + sx) * (K_DIM + 1) + c + 1],
                  0.015625f);              // 1/64
    }
}

extern "C" void kernel_launch(void* const* d_in, const int* in_sizes, int n_in,
                              void* d_out, int out_size, void* d_ws, size_t ws_size,
                              hipStream_t stream) {
    const float* x  = (const float*)d_in[0];       // (32, 256, 64, 64) fp32
    const float* cl = (const float*)d_in[1];       // (128, 256) fp32
    float* out = (float*)d_out;                    // (32, 64, 129) fp32

    unsigned short* Bt = (unsigned short*)d_ws;                  // 196608 B
    float* c2 = (float*)((char*)d_ws + 196608);                  // 512 B

    hipMemsetAsync(d_out, 0, (size_t)out_size, stream);
    prep_kernel<<<K_DIM, 64, 0, stream>>>(cl, Bt, c2);
    main_kernel<<<(N_IMG * PIX) / 128, 256, 0, stream>>>(x, Bt, c2, out);
}